// Round 1
// baseline (105.041 us; speedup 1.0000x reference)
//
#include <hip/hip_runtime.h>
#include <hip/hip_bf16.h>

// Problem constants (from reference): VOCAB=128000, K=2048, GS=128, G=16, B*S=32768.
#define KWIDTH 2048
#define NGROUP 16   // K / GS
// 256 threads/block, each thread does 8 consecutive elements -> one group per thread.

__global__ __launch_bounds__(256) void qembed_dequant_kernel(
    const int* __restrict__ x,        // [NTOK] token row indices
    const int* __restrict__ qw,       // [VOCAB, K] 4-bit codes stored as int32
    const float* __restrict__ scales, // [VOCAB, G]
    const int* __restrict__ zeros,    // [VOCAB, G]
    float* __restrict__ out)          // [NTOK, K]
{
    const int token = blockIdx.x;
    const int row = x[token];                  // wave-uniform (blockIdx-based)
    const int t = threadIdx.x;                 // 0..255
    const int g = t >> 4;                      // 16 threads per group of 128 elems

    const float s = scales[(size_t)row * NGROUP + g];
    const int   z = zeros [(size_t)row * NGROUP + g];

    const int4* qrow = reinterpret_cast<const int4*>(qw + (size_t)row * KWIDTH) + (t << 1);
    float4*     orow = reinterpret_cast<float4*>(out + (size_t)token * KWIDTH) + (t << 1);

    int4 q0 = qrow[0];
    int4 q1 = qrow[1];

    float4 o0, o1;
    o0.x = (float)(q0.x - z) * s;
    o0.y = (float)(q0.y - z) * s;
    o0.z = (float)(q0.z - z) * s;
    o0.w = (float)(q0.w - z) * s;
    o1.x = (float)(q1.x - z) * s;
    o1.y = (float)(q1.y - z) * s;
    o1.z = (float)(q1.z - z) * s;
    o1.w = (float)(q1.w - z) * s;

    orow[0] = o0;
    orow[1] = o1;
}

extern "C" void kernel_launch(void* const* d_in, const int* in_sizes, int n_in,
                              void* d_out, int out_size, void* d_ws, size_t ws_size,
                              hipStream_t stream) {
    const int*   x      = (const int*)d_in[0];
    const int*   qw     = (const int*)d_in[1];
    const float* scales = (const float*)d_in[2];
    const int*   zeros  = (const int*)d_in[3];
    float*       out    = (float*)d_out;

    const int n_tokens = in_sizes[0];          // B*S = 32768

    dim3 grid(n_tokens), block(256);
    qembed_dequant_kernel<<<grid, block, 0, stream>>>(x, qw, scales, zeros, out);
}

// Round 3
// 82.305 us; speedup vs baseline: 1.2762x; 1.2762x over previous
//
#include <hip/hip_runtime.h>
#include <hip/hip_bf16.h>

// Problem constants: VOCAB=128000, K=2048, GS=128, G=16, NTOK=B*S=32768.
#define KWIDTH 2048
#define NGROUP 16          // K / GS
#define TPB    512         // 8 waves; one 16B chunk (4 codes) per thread per token
#define TOKPB  2           // tokens per block -> 2 independent load->store chains/thread

typedef int   __attribute__((ext_vector_type(4))) intx4;
typedef float __attribute__((ext_vector_type(4))) floatx4;

__global__ __launch_bounds__(TPB) void qembed_dequant_kernel(
    const int* __restrict__ x,        // [NTOK]
    const int* __restrict__ qw,       // [VOCAB, K] 4-bit codes as int32
    const float* __restrict__ scales, // [VOCAB, G]
    const int* __restrict__ zeros,    // [VOCAB, G]
    float* __restrict__ out,          // [NTOK, K] fp32
    int n_tokens)
{
    const int t    = threadIdx.x;     // 0..511
    const int g    = t >> 5;          // element 4t -> group (4t)/128 = t/32
    const int tok0 = blockIdx.x * TOKPB;
    const int tok1 = tok0 + 1;

    const int row0 = x[tok0];
    const int row1 = (tok1 < n_tokens) ? x[tok1] : row0;

    // Lane-contiguous 16B loads: lane t reads bytes [16t, 16t+16) of the 8KB row.
    const intx4 q0 = reinterpret_cast<const intx4*>(qw + (size_t)row0 * KWIDTH)[t];
    const intx4 q1 = reinterpret_cast<const intx4*>(qw + (size_t)row1 * KWIDTH)[t];

    const float s0 = scales[(size_t)row0 * NGROUP + g];
    const int   z0 = zeros [(size_t)row0 * NGROUP + g];
    const float s1 = scales[(size_t)row1 * NGROUP + g];
    const int   z1 = zeros [(size_t)row1 * NGROUP + g];

    floatx4 o0, o1;
    o0.x = (float)(q0.x - z0) * s0;
    o0.y = (float)(q0.y - z0) * s0;
    o0.z = (float)(q0.z - z0) * s0;
    o0.w = (float)(q0.w - z0) * s0;
    o1.x = (float)(q1.x - z1) * s1;
    o1.y = (float)(q1.y - z1) * s1;
    o1.z = (float)(q1.z - z1) * s1;
    o1.w = (float)(q1.w - z1) * s1;

    // Streaming (nontemporal) stores: output is write-once, keep caches for qweight.
    floatx4* orow0 = reinterpret_cast<floatx4*>(out + (size_t)tok0 * KWIDTH) + t;
    __builtin_nontemporal_store(o0, orow0);
    if (tok1 < n_tokens) {
        floatx4* orow1 = reinterpret_cast<floatx4*>(out + (size_t)tok1 * KWIDTH) + t;
        __builtin_nontemporal_store(o1, orow1);
    }
}

extern "C" void kernel_launch(void* const* d_in, const int* in_sizes, int n_in,
                              void* d_out, int out_size, void* d_ws, size_t ws_size,
                              hipStream_t stream) {
    const int*   x      = (const int*)d_in[0];
    const int*   qw     = (const int*)d_in[1];
    const float* scales = (const float*)d_in[2];
    const int*   zeros  = (const int*)d_in[3];
    float*       out    = (float*)d_out;

    const int n_tokens = in_sizes[0];          // 32768
    const int n_blocks = (n_tokens + TOKPB - 1) / TOKPB;

    qembed_dequant_kernel<<<dim3(n_blocks), dim3(TPB), 0, stream>>>(
        x, qw, scales, zeros, out, n_tokens);
}